// Round 10
// baseline (16.694 us; speedup 1.0000x reference)
//
#include <hip/hip_runtime.h>

// Problem constants (match reference)
static constexpr int CB = 2;
static constexpr int CN = 256;
static constexpr int CK = 16;
static constexpr int NTRI = 136;              // K*(K+1)/2
#define F_ALPHA 0.01f
#define F_LAM   1.0f
#define F_KAPPA 1.0f
#define F_EPS   1e-6f
#define F_GCLIP 1000.0f

// triangle row offset: TRI(r) = r*(33-r)/2
#define TRIOFF(r) ((r)*(33-(r))/2)

// ---------------------------------------------------------------------------
// Kernel 1 (unchanged from R9): per (b,n):
//   R = expm(sum_a phi_a G_a)  (orthogonal; scale 1/16 + 8-term Taylor + 4 sq)
//   u = R^T mu_q                   -> wsUT[b][c][n]
//   W = R^T diag(1/(sig+eps)) R    (symmetric) -> upper tri wsWtri[b][e][n]
//   R -> wsR[b][n][16][16]
// ---------------------------------------------------------------------------
__global__ __launch_bounds__(256) void vfe_prep_kernel(
    const float* __restrict__ mu_q, const float* __restrict__ sigma_q,
    const float* __restrict__ phi, const float* __restrict__ gens,
    float* __restrict__ wsR, float* __restrict__ wsWtri, float* __restrict__ wsUT)
{
    const int bn = blockIdx.x;          // 0 .. B*N-1
    const int b  = bn >> 8;
    const int n  = bn & 255;
    const int t  = threadIdx.x;         // element (r,c)
    const int r  = t >> 4;
    const int c  = t & 15;

    __shared__ float Ms[256];
    __shared__ float Pa[256], Pb[256];
    __shared__ float Ta[256], Tb[256];
    __shared__ float Wst[256];
    __shared__ float msh[CK], dinv[CK];

    const float p0 = phi[bn*3+0];
    const float p1 = phi[bn*3+1];
    const float p2 = phi[bn*3+2];

    const float diag = (r == c) ? 1.0f : 0.0f;
    float m = p0*gens[t] + p1*gens[256+t] + p2*gens[512+t];
    m *= (1.0f/16.0f);                  // 4 squarings later
    Ms[t] = m;
    Pa[t] = m;
    if (t < CK) {
        msh[t]  = mu_q[bn*CK + t];
        dinv[t] = 1.0f / (fmaxf(sigma_q[bn*CK + t], F_EPS) + F_EPS);
    }
    __syncthreads();

    // cache column c of Ms in registers
    float mscol[CK];
    #pragma unroll
    for (int l = 0; l < CK; ++l) mscol[l] = Ms[l*CK + c];

    float Treg = diag + m;
    // Taylor k=2..8, ping-pong Pa/Pb, 1 barrier/iter
    #pragma unroll
    for (int k = 2; k <= 8; ++k) {
        const float* Pc = (k & 1) ? Pb : Pa;
        float*       Pn = (k & 1) ? Pa : Pb;
        float acc = 0.f;
        #pragma unroll
        for (int l = 0; l < CK; ++l) acc += Pc[r*CK+l] * mscol[l];
        acc *= (1.0f / (float)k);
        Pn[t] = acc;
        Treg += acc;
        __syncthreads();
    }

    // 4 squarings, ping-pong Ta/Tb; final lands in Ta
    Ta[t] = Treg;
    __syncthreads();
    #pragma unroll
    for (int s = 0; s < 4; ++s) {
        const float* Tc = (s & 1) ? Tb : Ta;
        float*       Tn = (s & 1) ? Ta : Tb;
        float acc = 0.f;
        #pragma unroll
        for (int l = 0; l < CK; ++l) acc += Tc[r*CK+l] * Tc[l*CK+c];
        Tn[t] = acc;
        __syncthreads();
    }
    // Ta = R (all lanes synced)

    // u = R^T mu (threads 0..15)
    if (t < CK) {
        float acc = 0.f;
        #pragma unroll
        for (int l = 0; l < CK; ++l) acc += Ta[l*CK+t] * msh[l];
        wsUT[(b*CK + t)*CN + n] = acc;
    }

    // R store: threads 64..127 write float4 chunks from Ta
    if (t >= 64 && t < 128) {
        const int g = t - 64;
        float4 v;
        v.x = Ta[4*g+0]; v.y = Ta[4*g+1]; v.z = Ta[4*g+2]; v.w = Ta[4*g+3];
        ((float4*)wsR)[bn*64 + g] = v;
    }

    // W element (r,c) -> Wst
    {
        float acc = 0.f;
        #pragma unroll
        for (int l = 0; l < CK; ++l) acc += Ta[l*CK+r] * dinv[l] * Ta[l*CK+c];
        Wst[t] = acc;
    }
    __syncthreads();

    // upper-triangle store: thread e<136 -> (re,ce), write [b][e][n]
    if (t < NTRI) {
        int re = 0;
        #pragma unroll
        for (int q = 1; q < 16; ++q) re += (t >= TRIOFF(q));
        const int ce = t - TRIOFF(re) + re;
        wsWtri[(b*NTRI + t)*CN + n] = Wst[re*CK + ce];
    }
}

// ---------------------------------------------------------------------------
// Kernel 2: 256 blocks x 512 threads; block = (b, i-pair), thread = (il, j).
// Same waves/CU as R9 (8), but threads t and t+256 share W_j loads via L1
// -> W L2-traffic halves. Reduction: 8-wave partials, il = wave>>2.
// ---------------------------------------------------------------------------
__global__ __launch_bounds__(512) void vfe_pair_kernel(
    const float* __restrict__ mu_q, const float* __restrict__ sigma_q,
    const float* __restrict__ mu_p, const float* __restrict__ sigma_p,
    const float* __restrict__ beta, const float* __restrict__ lr,
    const float* __restrict__ wsR, const float* __restrict__ wsWtri,
    const float* __restrict__ wsUT, float* __restrict__ out)
{
    const int bid = blockIdx.x;     // 0..255
    const int b   = bid >> 7;
    const int i0  = (bid & 127) * 2;
    const int t   = threadIdx.x;    // 0..511
    const int il  = t >> 8;         // which i of the pair
    const int j   = t & 255;

    __shared__ float uish[2][CK];
    __shared__ float Hs[2][256][17];
    __shared__ float bets[2][256];
    __shared__ float bkls[2][256];
    __shared__ float partS1[8][16];
    __shared__ float partS2[8][16];
    __shared__ float partS3[8];
    __shared__ float grot[2][CK];

    if (t < 32) uish[t >> 4][t & 15] = wsUT[(b*CK + (t & 15))*CN + i0 + (t >> 4)];
    __syncthreads();

    // ---- Phase A ----
    const float* uTb = wsUT + b*CK*CN;
    float d[CK];
    #pragma unroll
    for (int cc = 0; cc < CK; ++cc) d[cc] = uish[il][cc] - uTb[cc*CN + j];

    // h = W_j d via symmetric triangle (lane-coalesced b32; t and t+256 same j)
    const float* Wt = wsWtri + (size_t)b*NTRI*CN + j;
    float h[CK];
    #pragma unroll
    for (int q = 0; q < CK; ++q) h[q] = 0.f;
    {
        int e = 0;
        #pragma unroll
        for (int rr = 0; rr < CK; ++rr) {
            #pragma unroll
            for (int cc = rr; cc < CK; ++cc) {
                const float w = Wt[e*CN];
                h[rr] += w * d[cc];
                if (cc > rr) h[cc] += w * d[rr];
                ++e;
            }
        }
    }
    float kl = 0.f;
    #pragma unroll
    for (int q = 0; q < CK; ++q) { Hs[il][j][q] = h[q]; kl += h[q]*d[q]; }
    kl *= 0.5f;

    const float bt = beta[(b*CN + i0 + il)*CN + j];
    bets[il][j] = bt;
    bkls[il][j] = bt * kl;
    __syncthreads();

    // ---- Phase B: wave w handles il=w>>2; thread -> (jg, k) ----
    {
        const int k  = t & 15;
        const int jg = (t >> 4) & 15;   // 0..15 within this il-half
        float s1p = 0.f, s2p = 0.f, s3p = 0.f;
        #pragma unroll
        for (int s = 0; s < 16; ++s) {
            const int jj = jg*16 + s;
            const float hv = Hs[il][jj][k];
            const float be = bets[il][jj];
            const float bk = bkls[il][jj];
            s1p += be * hv;
            s2p += bk * hv;
            s3p += bk;
        }
        // reduce the 4 jg's resident in this wave (lanes l, l+16, l+32, l+48)
        s1p += __shfl_down(s1p, 16);  s1p += __shfl_down(s1p, 32);
        s2p += __shfl_down(s2p, 16);  s2p += __shfl_down(s2p, 32);
        s3p += __shfl_down(s3p, 16);  s3p += __shfl_down(s3p, 32);

        const int lane = t & 63;
        const int wv   = t >> 6;        // 0..7
        if (lane < 16) {
            partS1[wv][lane] = s1p;
            partS2[wv][lane] = s2p;
            if (lane == 0) partS3[wv] = s3p;
        }
    }
    __syncthreads();

    // ---- Phase C: t<32 -> (il2 = t>>4, k = t&15); waves il2*4..il2*4+3 ----
    if (t < 32) {
        const int il2 = t >> 4, k = t & 15, w0 = il2*4;
        const float s1 = partS1[w0][k] + partS1[w0+1][k] + partS1[w0+2][k] + partS1[w0+3][k];
        const float s2 = partS2[w0][k] + partS2[w0+1][k] + partS2[w0+2][k] + partS2[w0+3][k];
        const float s3 = partS3[w0] + partS3[w0+1] + partS3[w0+2] + partS3[w0+3];
        grot[il2][k] = F_LAM*s1 + (F_LAM/F_KAPPA)*(s2 - s3*s1);
    }
    __syncthreads();

    // ---- Epilogue: t<32 -> (il2, rr) ----
    if (t < 32) {
        const int il2 = t >> 4, rr = t & 15;
        const int i   = i0 + il2;
        const float* Ri = wsR + ((size_t)(b*CN + i))*256 + rr*CK;
        float acc = 0.f;
        #pragma unroll
        for (int cc = 0; cc < CK; ++cc) acc += Ri[cc] * grot[il2][cc];

        const int idx = (b*CN + i)*CK + rr;
        const float mq = mu_q[idx];
        const float sq = sigma_q[idx];
        const float mp = mu_p[idx];
        const float sp = sigma_p[idx];
        const float sps = fmaxf(sp, F_EPS);
        const float sqs = fmaxf(sq, F_EPS);

        const float gmu = F_ALPHA*(mq - mp)/sps + acc;
        const float gsg = F_ALPHA*0.5f*(1.0f/sps - 1.0f/sqs);

        float nmu = sqs * gmu;
        float nsg = 0.5f * sqs * sqs * gsg;
        nmu = fminf(fmaxf(nmu, -F_GCLIP), F_GCLIP);
        nsg = fminf(fmaxf(nsg, -F_GCLIP), F_GCLIP);

        const float step = lr[0];
        out[idx]             = mq - step*nmu;                 // mu_new
        out[CB*CN*CK + idx]  = fmaxf(sq - step*nsg, F_EPS);   // sigma_new
    }
}

extern "C" void kernel_launch(void* const* d_in, const int* in_sizes, int n_in,
                              void* d_out, int out_size, void* d_ws, size_t ws_size,
                              hipStream_t stream) {
    const float* mu_q    = (const float*)d_in[0];
    const float* sigma_q = (const float*)d_in[1];
    const float* mu_p    = (const float*)d_in[2];
    const float* sigma_p = (const float*)d_in[3];
    const float* beta    = (const float*)d_in[4];
    const float* phi     = (const float*)d_in[5];
    const float* gens    = (const float*)d_in[6];
    const float* lr      = (const float*)d_in[7];
    float* out = (float*)d_out;

    float* wsR    = (float*)d_ws;               // [b][n][16][16]
    float* wsWtri = wsR + CB*CN*CK*CK;          // [b][e<136][n]
    float* wsUT   = wsWtri + CB*NTRI*CN;        // [b][c][n]

    vfe_prep_kernel<<<CB*CN, 256, 0, stream>>>(mu_q, sigma_q, phi, gens,
                                               wsR, wsWtri, wsUT);
    vfe_pair_kernel<<<CB*CN/2, 512, 0, stream>>>(mu_q, sigma_q, mu_p, sigma_p, beta, lr,
                                                 wsR, wsWtri, wsUT, out);
}

// Round 11
// 16.418 us; speedup vs baseline: 1.0168x; 1.0168x over previous
//
#include <hip/hip_runtime.h>

// Problem constants (match reference)
static constexpr int CB = 2;
static constexpr int CN = 256;
static constexpr int CK = 16;
static constexpr int NTRI = 136;              // K*(K+1)/2
static constexpr int TS = 20;                 // transpose LDS stride (16B-aligned, conflict-free)
#define F_ALPHA 0.01f
#define F_LAM   1.0f
#define F_KAPPA 1.0f
#define F_EPS   1e-6f
#define F_GCLIP 1000.0f

// triangle row offset: TRI(r) = r*(33-r)/2
#define TRIOFF(r) ((r)*(33-(r))/2)

// ---------------------------------------------------------------------------
// Kernel 1: per (b,n):
//   R = expm(sum_a phi_a G_a)  (orthogonal; scale 1/16 + 8-term Taylor + 4 sq)
//   u = R^T mu_q                   -> wsUT[b][c][n]
//   W = R^T diag(1/(sig+eps)) R    (symmetric) -> upper tri wsWtri[b][e][n]
//   R -> wsR[b][n][16][16]
// All LDS matmul reads are ds_read_b128: rows of P/T are contiguous; a
// transpose copy (TaT/TbT, stride TS=20) makes columns contiguous too.
// DS instrs/thread ~280 -> ~90 vs R9.
// ---------------------------------------------------------------------------
__global__ __launch_bounds__(256) void vfe_prep_kernel(
    const float* __restrict__ mu_q, const float* __restrict__ sigma_q,
    const float* __restrict__ phi, const float* __restrict__ gens,
    float* __restrict__ wsR, float* __restrict__ wsWtri, float* __restrict__ wsUT)
{
    const int bn = blockIdx.x;          // 0 .. B*N-1
    const int b  = bn >> 8;
    const int n  = bn & 255;
    const int t  = threadIdx.x;         // element (r,c)
    const int r  = t >> 4;
    const int c  = t & 15;

    __shared__ __align__(16) float Ms[256];
    __shared__ __align__(16) float Pa[256], Pb[256];
    __shared__ __align__(16) float Ta[256], Tb[256];
    __shared__ __align__(16) float TaT[16*TS], TbT[16*TS];
    __shared__ __align__(16) float Wst[256];
    __shared__ __align__(16) float msh[CK], dinv[CK];

    const float p0 = phi[bn*3+0];
    const float p1 = phi[bn*3+1];
    const float p2 = phi[bn*3+2];

    const float diag = (r == c) ? 1.0f : 0.0f;
    float m = p0*gens[t] + p1*gens[256+t] + p2*gens[512+t];
    m *= (1.0f/16.0f);                  // 4 squarings later
    Ms[t] = m;
    Pa[t] = m;
    if (t < CK) {
        msh[t]  = mu_q[bn*CK + t];
        dinv[t] = 1.0f / (fmaxf(sigma_q[bn*CK + t], F_EPS) + F_EPS);
    }
    __syncthreads();

    // cache column c of Ms in registers (read once)
    float mscol[CK];
    #pragma unroll
    for (int l = 0; l < CK; ++l) mscol[l] = Ms[l*CK + c];

    float Treg = diag + m;
    // Taylor k=2..8, ping-pong Pa/Pb, 1 barrier/iter; row reads as float4
    #pragma unroll
    for (int k = 2; k <= 8; ++k) {
        const float* Pc = (k & 1) ? Pb : Pa;
        float*       Pn = (k & 1) ? Pa : Pb;
        const float4* Pr = (const float4*)(Pc + r*CK);
        float acc = 0.f;
        #pragma unroll
        for (int q = 0; q < 4; ++q) {
            const float4 pv = Pr[q];
            acc += pv.x*mscol[4*q+0] + pv.y*mscol[4*q+1]
                 + pv.z*mscol[4*q+2] + pv.w*mscol[4*q+3];
        }
        acc *= (1.0f / (float)k);
        Pn[t] = acc;
        Treg += acc;
        __syncthreads();
    }

    // 4 squarings, ping-pong (Ta,TaT)/(Tb,TbT); final lands in Ta/TaT
    Ta[t] = Treg;
    TaT[c*TS + r] = Treg;
    __syncthreads();
    #pragma unroll
    for (int s = 0; s < 4; ++s) {
        const float* Tc  = (s & 1) ? Tb  : Ta;
        const float* TcT = (s & 1) ? TbT : TaT;
        float*       Tn  = (s & 1) ? Ta  : Tb;
        float*       TnT = (s & 1) ? TaT : TbT;
        const float4* Rr = (const float4*)(Tc  + r*CK);
        const float4* Cc = (const float4*)(TcT + c*TS);
        float acc = 0.f;
        #pragma unroll
        for (int q = 0; q < 4; ++q) {
            const float4 a = Rr[q];
            const float4 bv = Cc[q];
            acc += a.x*bv.x + a.y*bv.y + a.z*bv.z + a.w*bv.w;
        }
        Tn[t] = acc;
        TnT[c*TS + r] = acc;
        __syncthreads();
    }
    // Ta = R, TaT = R^T (stride TS)

    // u = R^T mu (threads 0..15): row t of R^T, contiguous
    if (t < CK) {
        const float4* Rt = (const float4*)(TaT + t*TS);
        const float4* mh = (const float4*)msh;
        float acc = 0.f;
        #pragma unroll
        for (int q = 0; q < 4; ++q) {
            const float4 a = Rt[q];
            const float4 mm = mh[q];
            acc += a.x*mm.x + a.y*mm.y + a.z*mm.z + a.w*mm.w;
        }
        wsUT[(b*CK + t)*CN + n] = acc;
    }

    // R store: threads 64..127 write float4 chunks from Ta
    if (t >= 64 && t < 128) {
        const int g = t - 64;
        float4 v;
        v.x = Ta[4*g+0]; v.y = Ta[4*g+1]; v.z = Ta[4*g+2]; v.w = Ta[4*g+3];
        ((float4*)wsR)[bn*64 + g] = v;
    }

    // W element (r,c) = sum_l R[l,r] dinv[l] R[l,c]  (rows r,c of R^T)
    {
        const float4* Rr = (const float4*)(TaT + r*TS);
        const float4* Rc = (const float4*)(TaT + c*TS);
        const float4* dv = (const float4*)dinv;
        float acc = 0.f;
        #pragma unroll
        for (int q = 0; q < 4; ++q) {
            const float4 a = Rr[q];
            const float4 bb = Rc[q];
            const float4 dd = dv[q];
            acc += a.x*dd.x*bb.x + a.y*dd.y*bb.y + a.z*dd.z*bb.z + a.w*dd.w*bb.w;
        }
        Wst[t] = acc;
    }
    __syncthreads();

    // upper-triangle store: thread e<136 -> (re,ce), write [b][e][n]
    if (t < NTRI) {
        int re = 0;
        #pragma unroll
        for (int q = 1; q < 16; ++q) re += (t >= TRIOFF(q));
        const int ce = t - TRIOFF(re) + re;
        wsWtri[(b*NTRI + t)*CN + n] = Wst[re*CK + ce];
    }
}

// ---------------------------------------------------------------------------
// Kernel 2 (R9 verbatim; best-known config): one block per (b,i), thread = j.
//   Phase A: d = u_i - u_j; h = W_j d via symmetric triangle; kl = 0.5 d.h
//   Phase B: H-in-LDS partial dots; Phase C + epilogue.
// ---------------------------------------------------------------------------
__global__ __launch_bounds__(256) void vfe_pair_kernel(
    const float* __restrict__ mu_q, const float* __restrict__ sigma_q,
    const float* __restrict__ mu_p, const float* __restrict__ sigma_p,
    const float* __restrict__ beta, const float* __restrict__ lr,
    const float* __restrict__ wsR, const float* __restrict__ wsWtri,
    const float* __restrict__ wsUT, float* __restrict__ out)
{
    const int bi = blockIdx.x;      // b*N + i
    const int b  = bi >> 8;
    const int i  = bi & 255;
    const int t  = threadIdx.x;     // 0..255 (= j in phase A)

    __shared__ float uish[CK];
    __shared__ float Hs[256][17];
    __shared__ float bets[256];
    __shared__ float bkls[256];
    __shared__ float partS1[4][16];
    __shared__ float partS2[4][16];
    __shared__ float partS3[4];
    __shared__ float grot[CK];

    if (t < CK) uish[t] = wsUT[(b*CK + t)*CN + i];
    __syncthreads();

    // ---- Phase A ----
    const float* uTb = wsUT + b*CK*CN;
    float d[CK];
    #pragma unroll
    for (int cc = 0; cc < CK; ++cc) d[cc] = uish[cc] - uTb[cc*CN + t];

    // h = W_j d via symmetric triangle (lane-coalesced b32 loads)
    const float* Wt = wsWtri + (size_t)b*NTRI*CN + t;
    float h[CK];
    #pragma unroll
    for (int q = 0; q < CK; ++q) h[q] = 0.f;
    {
        int e = 0;
        #pragma unroll
        for (int rr = 0; rr < CK; ++rr) {
            #pragma unroll
            for (int cc = rr; cc < CK; ++cc) {
                const float w = Wt[e*CN];
                h[rr] += w * d[cc];
                if (cc > rr) h[cc] += w * d[rr];
                ++e;
            }
        }
    }
    float kl = 0.f;
    #pragma unroll
    for (int q = 0; q < CK; ++q) { Hs[t][q] = h[q]; kl += h[q]*d[q]; }
    kl *= 0.5f;

    const float bt = beta[(b*CN + i)*CN + t];
    bets[t] = bt;
    bkls[t] = bt * kl;
    __syncthreads();

    // ---- Phase B: thread = (jg = t>>4, k = t&15) ----
    {
        const int k  = t & 15;
        const int jg = t >> 4;
        float s1p = 0.f, s2p = 0.f, s3p = 0.f;
        #pragma unroll
        for (int s = 0; s < 16; ++s) {
            const int jj = jg*16 + s;
            const float hv = Hs[jj][k];
            const float be = bets[jj];
            const float bk = bkls[jj];
            s1p += be * hv;
            s2p += bk * hv;
            s3p += bk;
        }
        s1p += __shfl_down(s1p, 16);  s1p += __shfl_down(s1p, 32);
        s2p += __shfl_down(s2p, 16);  s2p += __shfl_down(s2p, 32);
        s3p += __shfl_down(s3p, 16);  s3p += __shfl_down(s3p, 32);

        const int lane = t & 63;
        const int wv   = t >> 6;
        if (lane < 16) {
            partS1[wv][lane] = s1p;
            partS2[wv][lane] = s2p;
            if (lane == 0) partS3[wv] = s3p;
        }
    }
    __syncthreads();

    // ---- Phase C ----
    if (t < CK) {
        const float s1 = partS1[0][t] + partS1[1][t] + partS1[2][t] + partS1[3][t];
        const float s2 = partS2[0][t] + partS2[1][t] + partS2[2][t] + partS2[3][t];
        const float s3 = partS3[0] + partS3[1] + partS3[2] + partS3[3];
        grot[t] = F_LAM*s1 + (F_LAM/F_KAPPA)*(s2 - s3*s1);
    }
    __syncthreads();

    // ---- Epilogue ----
    if (t < CK) {
        const int rr = t;
        const float* Ri = wsR + bi*256;
        float acc = 0.f;
        #pragma unroll
        for (int cc = 0; cc < CK; ++cc) acc += Ri[rr*CK+cc] * grot[cc];

        const int idx = bi*CK + rr;
        const float mq = mu_q[idx];
        const float sq = sigma_q[idx];
        const float mp = mu_p[idx];
        const float sp = sigma_p[idx];
        const float sps = fmaxf(sp, F_EPS);
        const float sqs = fmaxf(sq, F_EPS);

        const float gmu = F_ALPHA*(mq - mp)/sps + acc;
        const float gsg = F_ALPHA*0.5f*(1.0f/sps - 1.0f/sqs);

        float nmu = sqs * gmu;
        float nsg = 0.5f * sqs * sqs * gsg;
        nmu = fminf(fmaxf(nmu, -F_GCLIP), F_GCLIP);
        nsg = fminf(fmaxf(nsg, -F_GCLIP), F_GCLIP);

        const float step = lr[0];
        out[idx]             = mq - step*nmu;                 // mu_new
        out[CB*CN*CK + idx]  = fmaxf(sq - step*nsg, F_EPS);   // sigma_new
    }
}

extern "C" void kernel_launch(void* const* d_in, const int* in_sizes, int n_in,
                              void* d_out, int out_size, void* d_ws, size_t ws_size,
                              hipStream_t stream) {
    const float* mu_q    = (const float*)d_in[0];
    const float* sigma_q = (const float*)d_in[1];
    const float* mu_p    = (const float*)d_in[2];
    const float* sigma_p = (const float*)d_in[3];
    const float* beta    = (const float*)d_in[4];
    const float* phi     = (const float*)d_in[5];
    const float* gens    = (const float*)d_in[6];
    const float* lr      = (const float*)d_in[7];
    float* out = (float*)d_out;

    float* wsR    = (float*)d_ws;               // [b][n][16][16]
    float* wsWtri = wsR + CB*CN*CK*CK;          // [b][e<136][n]
    float* wsUT   = wsWtri + CB*NTRI*CN;        // [b][c][n]

    vfe_prep_kernel<<<CB*CN, 256, 0, stream>>>(mu_q, sigma_q, phi, gens,
                                               wsR, wsWtri, wsUT);
    vfe_pair_kernel<<<CB*CN, 256, 0, stream>>>(mu_q, sigma_q, mu_p, sigma_p, beta, lr,
                                               wsR, wsWtri, wsUT, out);
}

// Round 12
// 16.024 us; speedup vs baseline: 1.0418x; 1.0246x over previous
//
#include <hip/hip_runtime.h>
#include <hip/hip_fp16.h>

// Problem constants (match reference)
static constexpr int CB = 2;
static constexpr int CN = 256;
static constexpr int CK = 16;
static constexpr int NTRI = 136;              // K*(K+1)/2
static constexpr int TS = 20;                 // transpose LDS stride
#define F_ALPHA 0.01f
#define F_LAM   1.0f
#define F_KAPPA 1.0f
#define F_EPS   1e-6f
#define F_GCLIP 1000.0f

// triangle row offset: TRI(r) = r*(33-r)/2
#define TRIOFF(r) ((r)*(33-(r))/2)

// ---------------------------------------------------------------------------
// Kernel 1 (R11 structure): per (b,n):
//   R = expm(sum_a phi_a G_a)  (orthogonal; scale 1/16 + 8-term Taylor + 4 sq)
//   u = R^T mu_q                   -> wsUT[b][c][n]  (fp32)
//   W = R^T diag(1/(sig+eps)) R    (symmetric) -> upper tri wsWtriH[b][e][n] FP16
//   R -> wsR[b][n][16][16]  (fp32)
// ---------------------------------------------------------------------------
__global__ __launch_bounds__(256) void vfe_prep_kernel(
    const float* __restrict__ mu_q, const float* __restrict__ sigma_q,
    const float* __restrict__ phi, const float* __restrict__ gens,
    float* __restrict__ wsR, __half* __restrict__ wsWtriH, float* __restrict__ wsUT)
{
    const int bn = blockIdx.x;          // 0 .. B*N-1
    const int b  = bn >> 8;
    const int n  = bn & 255;
    const int t  = threadIdx.x;         // element (r,c)
    const int r  = t >> 4;
    const int c  = t & 15;

    __shared__ __align__(16) float Ms[256];
    __shared__ __align__(16) float Pa[256], Pb[256];
    __shared__ __align__(16) float Ta[256], Tb[256];
    __shared__ __align__(16) float TaT[16*TS], TbT[16*TS];
    __shared__ __align__(16) float Wst[256];
    __shared__ __align__(16) float msh[CK], dinv[CK];

    const float p0 = phi[bn*3+0];
    const float p1 = phi[bn*3+1];
    const float p2 = phi[bn*3+2];

    const float diag = (r == c) ? 1.0f : 0.0f;
    float m = p0*gens[t] + p1*gens[256+t] + p2*gens[512+t];
    m *= (1.0f/16.0f);                  // 4 squarings later
    Ms[t] = m;
    Pa[t] = m;
    if (t < CK) {
        msh[t]  = mu_q[bn*CK + t];
        dinv[t] = 1.0f / (fmaxf(sigma_q[bn*CK + t], F_EPS) + F_EPS);
    }
    __syncthreads();

    // cache column c of Ms in registers (read once)
    float mscol[CK];
    #pragma unroll
    for (int l = 0; l < CK; ++l) mscol[l] = Ms[l*CK + c];

    float Treg = diag + m;
    // Taylor k=2..8, ping-pong Pa/Pb, 1 barrier/iter; row reads as float4
    #pragma unroll
    for (int k = 2; k <= 8; ++k) {
        const float* Pc = (k & 1) ? Pb : Pa;
        float*       Pn = (k & 1) ? Pa : Pb;
        const float4* Pr = (const float4*)(Pc + r*CK);
        float acc = 0.f;
        #pragma unroll
        for (int q = 0; q < 4; ++q) {
            const float4 pv = Pr[q];
            acc += pv.x*mscol[4*q+0] + pv.y*mscol[4*q+1]
                 + pv.z*mscol[4*q+2] + pv.w*mscol[4*q+3];
        }
        acc *= (1.0f / (float)k);
        Pn[t] = acc;
        Treg += acc;
        __syncthreads();
    }

    // 4 squarings, ping-pong (Ta,TaT)/(Tb,TbT); final lands in Ta/TaT
    Ta[t] = Treg;
    TaT[c*TS + r] = Treg;
    __syncthreads();
    #pragma unroll
    for (int s = 0; s < 4; ++s) {
        const float* Tc  = (s & 1) ? Tb  : Ta;
        const float* TcT = (s & 1) ? TbT : TaT;
        float*       Tn  = (s & 1) ? Ta  : Tb;
        float*       TnT = (s & 1) ? TaT : TbT;
        const float4* Rr = (const float4*)(Tc  + r*CK);
        const float4* Cc = (const float4*)(TcT + c*TS);
        float acc = 0.f;
        #pragma unroll
        for (int q = 0; q < 4; ++q) {
            const float4 a = Rr[q];
            const float4 bv = Cc[q];
            acc += a.x*bv.x + a.y*bv.y + a.z*bv.z + a.w*bv.w;
        }
        Tn[t] = acc;
        TnT[c*TS + r] = acc;
        __syncthreads();
    }
    // Ta = R, TaT = R^T (stride TS)

    // u = R^T mu (threads 0..15): row t of R^T, contiguous
    if (t < CK) {
        const float4* Rt = (const float4*)(TaT + t*TS);
        const float4* mh = (const float4*)msh;
        float acc = 0.f;
        #pragma unroll
        for (int q = 0; q < 4; ++q) {
            const float4 a = Rt[q];
            const float4 mm = mh[q];
            acc += a.x*mm.x + a.y*mm.y + a.z*mm.z + a.w*mm.w;
        }
        wsUT[(b*CK + t)*CN + n] = acc;
    }

    // R store: threads 64..127 write float4 chunks from Ta
    if (t >= 64 && t < 128) {
        const int g = t - 64;
        float4 v;
        v.x = Ta[4*g+0]; v.y = Ta[4*g+1]; v.z = Ta[4*g+2]; v.w = Ta[4*g+3];
        ((float4*)wsR)[bn*64 + g] = v;
    }

    // W element (r,c) = sum_l R[l,r] dinv[l] R[l,c]  (rows r,c of R^T)
    {
        const float4* Rr = (const float4*)(TaT + r*TS);
        const float4* Rc = (const float4*)(TaT + c*TS);
        const float4* dv = (const float4*)dinv;
        float acc = 0.f;
        #pragma unroll
        for (int q = 0; q < 4; ++q) {
            const float4 a = Rr[q];
            const float4 bb = Rc[q];
            const float4 dd = dv[q];
            acc += a.x*dd.x*bb.x + a.y*dd.y*bb.y + a.z*dd.z*bb.z + a.w*dd.w*bb.w;
        }
        Wst[t] = acc;
    }
    __syncthreads();

    // upper-triangle store (FP16): thread e<136 -> (re,ce), write [b][e][n]
    if (t < NTRI) {
        int re = 0;
        #pragma unroll
        for (int q = 1; q < 16; ++q) re += (t >= TRIOFF(q));
        const int ce = t - TRIOFF(re) + re;
        wsWtriH[(b*NTRI + t)*CN + n] = __float2half_rn(Wst[re*CK + ce]);
    }
}

// ---------------------------------------------------------------------------
// Kernel 2 (R9 structure; W triangle read as FP16 -> half traffic):
//   Phase A: d = u_i - u_j; h = W_j d via symmetric triangle; kl = 0.5 d.h
//   Phase B: H-in-LDS partial dots; Phase C + epilogue.
// ---------------------------------------------------------------------------
__global__ __launch_bounds__(256) void vfe_pair_kernel(
    const float* __restrict__ mu_q, const float* __restrict__ sigma_q,
    const float* __restrict__ mu_p, const float* __restrict__ sigma_p,
    const float* __restrict__ beta, const float* __restrict__ lr,
    const float* __restrict__ wsR, const __half* __restrict__ wsWtriH,
    const float* __restrict__ wsUT, float* __restrict__ out)
{
    const int bi = blockIdx.x;      // b*N + i
    const int b  = bi >> 8;
    const int i  = bi & 255;
    const int t  = threadIdx.x;     // 0..255 (= j in phase A)

    __shared__ float uish[CK];
    __shared__ float Hs[256][17];
    __shared__ float bets[256];
    __shared__ float bkls[256];
    __shared__ float partS1[4][16];
    __shared__ float partS2[4][16];
    __shared__ float partS3[4];
    __shared__ float grot[CK];

    if (t < CK) uish[t] = wsUT[(b*CK + t)*CN + i];
    __syncthreads();

    // ---- Phase A ----
    const float* uTb = wsUT + b*CK*CN;
    float d[CK];
    #pragma unroll
    for (int cc = 0; cc < CK; ++cc) d[cc] = uish[cc] - uTb[cc*CN + t];

    // h = W_j d via symmetric triangle (lane-coalesced u16 loads)
    const __half* Wt = wsWtriH + (size_t)b*NTRI*CN + t;
    float h[CK];
    #pragma unroll
    for (int q = 0; q < CK; ++q) h[q] = 0.f;
    {
        int e = 0;
        #pragma unroll
        for (int rr = 0; rr < CK; ++rr) {
            #pragma unroll
            for (int cc = rr; cc < CK; ++cc) {
                const float w = __half2float(Wt[e*CN]);
                h[rr] += w * d[cc];
                if (cc > rr) h[cc] += w * d[rr];
                ++e;
            }
        }
    }
    float kl = 0.f;
    #pragma unroll
    for (int q = 0; q < CK; ++q) { Hs[t][q] = h[q]; kl += h[q]*d[q]; }
    kl *= 0.5f;

    const float bt = beta[(b*CN + i)*CN + t];
    bets[t] = bt;
    bkls[t] = bt * kl;
    __syncthreads();

    // ---- Phase B: thread = (jg = t>>4, k = t&15) ----
    {
        const int k  = t & 15;
        const int jg = t >> 4;
        float s1p = 0.f, s2p = 0.f, s3p = 0.f;
        #pragma unroll
        for (int s = 0; s < 16; ++s) {
            const int jj = jg*16 + s;
            const float hv = Hs[jj][k];
            const float be = bets[jj];
            const float bk = bkls[jj];
            s1p += be * hv;
            s2p += bk * hv;
            s3p += bk;
        }
        s1p += __shfl_down(s1p, 16);  s1p += __shfl_down(s1p, 32);
        s2p += __shfl_down(s2p, 16);  s2p += __shfl_down(s2p, 32);
        s3p += __shfl_down(s3p, 16);  s3p += __shfl_down(s3p, 32);

        const int lane = t & 63;
        const int wv   = t >> 6;
        if (lane < 16) {
            partS1[wv][lane] = s1p;
            partS2[wv][lane] = s2p;
            if (lane == 0) partS3[wv] = s3p;
        }
    }
    __syncthreads();

    // ---- Phase C ----
    if (t < CK) {
        const float s1 = partS1[0][t] + partS1[1][t] + partS1[2][t] + partS1[3][t];
        const float s2 = partS2[0][t] + partS2[1][t] + partS2[2][t] + partS2[3][t];
        const float s3 = partS3[0] + partS3[1] + partS3[2] + partS3[3];
        grot[t] = F_LAM*s1 + (F_LAM/F_KAPPA)*(s2 - s3*s1);
    }
    __syncthreads();

    // ---- Epilogue ----
    if (t < CK) {
        const int rr = t;
        const float* Ri = wsR + bi*256;
        float acc = 0.f;
        #pragma unroll
        for (int cc = 0; cc < CK; ++cc) acc += Ri[rr*CK+cc] * grot[cc];

        const int idx = bi*CK + rr;
        const float mq = mu_q[idx];
        const float sq = sigma_q[idx];
        const float mp = mu_p[idx];
        const float sp = sigma_p[idx];
        const float sps = fmaxf(sp, F_EPS);
        const float sqs = fmaxf(sq, F_EPS);

        const float gmu = F_ALPHA*(mq - mp)/sps + acc;
        const float gsg = F_ALPHA*0.5f*(1.0f/sps - 1.0f/sqs);

        float nmu = sqs * gmu;
        float nsg = 0.5f * sqs * sqs * gsg;
        nmu = fminf(fmaxf(nmu, -F_GCLIP), F_GCLIP);
        nsg = fminf(fmaxf(nsg, -F_GCLIP), F_GCLIP);

        const float step = lr[0];
        out[idx]             = mq - step*nmu;                 // mu_new
        out[CB*CN*CK + idx]  = fmaxf(sq - step*nsg, F_EPS);   // sigma_new
    }
}

extern "C" void kernel_launch(void* const* d_in, const int* in_sizes, int n_in,
                              void* d_out, int out_size, void* d_ws, size_t ws_size,
                              hipStream_t stream) {
    const float* mu_q    = (const float*)d_in[0];
    const float* sigma_q = (const float*)d_in[1];
    const float* mu_p    = (const float*)d_in[2];
    const float* sigma_p = (const float*)d_in[3];
    const float* beta    = (const float*)d_in[4];
    const float* phi     = (const float*)d_in[5];
    const float* gens    = (const float*)d_in[6];
    const float* lr      = (const float*)d_in[7];
    float* out = (float*)d_out;

    float*  wsR     = (float*)d_ws;                 // [b][n][16][16] fp32
    __half* wsWtriH = (__half*)(wsR + CB*CN*CK*CK); // [b][e<136][n] fp16 (69632 halves)
    float*  wsUT    = (float*)((char*)wsWtriH + ((CB*NTRI*CN*sizeof(__half) + 15) & ~15));

    vfe_prep_kernel<<<CB*CN, 256, 0, stream>>>(mu_q, sigma_q, phi, gens,
                                               wsR, wsWtriH, wsUT);
    vfe_pair_kernel<<<CB*CN, 256, 0, stream>>>(mu_q, sigma_q, mu_p, sigma_p, beta, lr,
                                               wsR, wsWtriH, wsUT, out);
}

// Round 13
// 15.451 us; speedup vs baseline: 1.0804x; 1.0371x over previous
//
#include <hip/hip_runtime.h>
#include <hip/hip_fp16.h>

// Problem constants (match reference)
static constexpr int CB = 2;
static constexpr int CN = 256;
static constexpr int CK = 16;
static constexpr int TS = 20;                 // transpose LDS stride
#define F_ALPHA 0.01f
#define F_LAM   1.0f
#define F_KAPPA 1.0f
#define F_EPS   1e-6f
#define F_GCLIP 1000.0f

typedef _Float16 h2_t __attribute__((ext_vector_type(2)));
__device__ inline h2_t as_h2(unsigned u) { union { unsigned u; h2_t h; } x; x.u = u; return x.h; }

#if __has_builtin(__builtin_amdgcn_fdot2)
#define FDOT2(a, b, c) __builtin_amdgcn_fdot2((a), (b), (c), false)
#else
#define FDOT2(a, b, c) ((c) + (float)(a).x * (float)(b).x + (float)(a).y * (float)(b).y)
#endif

// ---------------------------------------------------------------------------
// Kernel 1: per (b,n):
//   R = expm(sum_a phi_a G_a)  (orthogonal; scale 1/8 + Taylor k<=6 + 3 sq;
//       worst-case ||X||~0.33 -> remainder ~7e-8)
//   u = R^T mu_q                -> wsUT[b][c][n]  (fp32)
//   W = R^T diag(1/(sig+eps)) R -> full row-major FP16, packed 8/16B:
//       wsW16[b][g<32][n][8]   (g = element/8)
//   R -> wsR[b][n][16][16]  (fp32)
// ---------------------------------------------------------------------------
__global__ __launch_bounds__(256) void vfe_prep_kernel(
    const float* __restrict__ mu_q, const float* __restrict__ sigma_q,
    const float* __restrict__ phi, const float* __restrict__ gens,
    float* __restrict__ wsR, unsigned* __restrict__ wsW16, float* __restrict__ wsUT)
{
    const int bn = blockIdx.x;          // 0 .. B*N-1
    const int b  = bn >> 8;
    const int n  = bn & 255;
    const int t  = threadIdx.x;         // element (r,c)
    const int r  = t >> 4;
    const int c  = t & 15;

    __shared__ __align__(16) float Ms[256];
    __shared__ __align__(16) float Pa[256], Pb[256];
    __shared__ __align__(16) float Ta[256], Tb[256];
    __shared__ __align__(16) float TaT[16*TS], TbT[16*TS];
    __shared__ __align__(16) float Wst[256];
    __shared__ __align__(16) float msh[CK], dinv[CK];

    const float p0 = phi[bn*3+0];
    const float p1 = phi[bn*3+1];
    const float p2 = phi[bn*3+2];

    const float diag = (r == c) ? 1.0f : 0.0f;
    float m = p0*gens[t] + p1*gens[256+t] + p2*gens[512+t];
    m *= (1.0f/8.0f);                   // 3 squarings later
    Ms[t] = m;
    Pa[t] = m;
    if (t < CK) {
        msh[t]  = mu_q[bn*CK + t];
        dinv[t] = 1.0f / (fmaxf(sigma_q[bn*CK + t], F_EPS) + F_EPS);
    }
    __syncthreads();

    // cache column c of Ms in registers (read once)
    float mscol[CK];
    #pragma unroll
    for (int l = 0; l < CK; ++l) mscol[l] = Ms[l*CK + c];

    float Treg = diag + m;
    // Taylor k=2..6, ping-pong Pa/Pb, 1 barrier/iter; row reads as float4
    #pragma unroll
    for (int k = 2; k <= 6; ++k) {
        const float* Pc = (k & 1) ? Pb : Pa;
        float*       Pn = (k & 1) ? Pa : Pb;
        const float4* Pr = (const float4*)(Pc + r*CK);
        float acc = 0.f;
        #pragma unroll
        for (int q = 0; q < 4; ++q) {
            const float4 pv = Pr[q];
            acc += pv.x*mscol[4*q+0] + pv.y*mscol[4*q+1]
                 + pv.z*mscol[4*q+2] + pv.w*mscol[4*q+3];
        }
        acc *= (1.0f / (float)k);
        Pn[t] = acc;
        Treg += acc;
        __syncthreads();
    }

    // 3 squarings, ping-pong; final lands in Tb/TbT
    Ta[t] = Treg;
    TaT[c*TS + r] = Treg;
    __syncthreads();
    #pragma unroll
    for (int s = 0; s < 3; ++s) {
        const float* Tc  = (s & 1) ? Tb  : Ta;
        const float* TcT = (s & 1) ? TbT : TaT;
        float*       Tn  = (s & 1) ? Ta  : Tb;
        float*       TnT = (s & 1) ? TaT : TbT;
        const float4* Rr = (const float4*)(Tc  + r*CK);
        const float4* Cc = (const float4*)(TcT + c*TS);
        float acc = 0.f;
        #pragma unroll
        for (int q = 0; q < 4; ++q) {
            const float4 a = Rr[q];
            const float4 bv = Cc[q];
            acc += a.x*bv.x + a.y*bv.y + a.z*bv.z + a.w*bv.w;
        }
        Tn[t] = acc;
        TnT[c*TS + r] = acc;
        __syncthreads();
    }
    // Tb = R, TbT = R^T (stride TS)

    // u = R^T mu (threads 0..15): row t of R^T, contiguous
    if (t < CK) {
        const float4* Rt = (const float4*)(TbT + t*TS);
        const float4* mh = (const float4*)msh;
        float acc = 0.f;
        #pragma unroll
        for (int q = 0; q < 4; ++q) {
            const float4 a = Rt[q];
            const float4 mm = mh[q];
            acc += a.x*mm.x + a.y*mm.y + a.z*mm.z + a.w*mm.w;
        }
        wsUT[(b*CK + t)*CN + n] = acc;
    }

    // R store: threads 64..127 write float4 chunks from Tb
    if (t >= 64 && t < 128) {
        const int g = t - 64;
        float4 v;
        v.x = Tb[4*g+0]; v.y = Tb[4*g+1]; v.z = Tb[4*g+2]; v.w = Tb[4*g+3];
        ((float4*)wsR)[bn*64 + g] = v;
    }

    // W element (r,c) = sum_l R[l,r] dinv[l] R[l,c]  (rows r,c of R^T)
    {
        const float4* Rr = (const float4*)(TbT + r*TS);
        const float4* Rc = (const float4*)(TbT + c*TS);
        const float4* dv = (const float4*)dinv;
        float acc = 0.f;
        #pragma unroll
        for (int q = 0; q < 4; ++q) {
            const float4 a = Rr[q];
            const float4 bb = Rc[q];
            const float4 dd = dv[q];
            acc += a.x*dd.x*bb.x + a.y*dd.y*bb.y + a.z*dd.z*bb.z + a.w*dd.w*bb.w;
        }
        Wst[t] = acc;
    }
    __syncthreads();

    // packed fp16 store: thread g<32 packs Wst[8g..8g+8) -> uint4 at [b][g][n]
    if (t < 32) {
        const int g = t;
        unsigned pk[4];
        #pragma unroll
        for (int q = 0; q < 4; ++q) {
            __half2 p = __floats2half2_rn(Wst[g*8 + 2*q], Wst[g*8 + 2*q + 1]);
            pk[q] = *reinterpret_cast<unsigned*>(&p);
        }
        uint4 v; v.x = pk[0]; v.y = pk[1]; v.z = pk[2]; v.w = pk[3];
        ((uint4*)wsW16)[(size_t)(b*32 + g)*CN + n] = v;
    }
}

// ---------------------------------------------------------------------------
// Kernel 2 (R9/R12 structure; W as packed fp16 rows + v_dot2):
//   Phase A: d = u_i - u_j (fp32 -> half2); h[r] = sum_g fdot2(Wrow, d) fp32;
//            kl = 0.5 d.h (fp32)
//   Phase B: H-in-LDS partial dots; Phase C + epilogue (unchanged).
// ---------------------------------------------------------------------------
__global__ __launch_bounds__(256) void vfe_pair_kernel(
    const float* __restrict__ mu_q, const float* __restrict__ sigma_q,
    const float* __restrict__ mu_p, const float* __restrict__ sigma_p,
    const float* __restrict__ beta, const float* __restrict__ lr,
    const float* __restrict__ wsR, const unsigned* __restrict__ wsW16,
    const float* __restrict__ wsUT, float* __restrict__ out)
{
    const int bi = blockIdx.x;      // b*N + i
    const int b  = bi >> 8;
    const int i  = bi & 255;
    const int t  = threadIdx.x;     // 0..255 (= j in phase A)

    __shared__ float uish[CK];
    __shared__ float Hs[256][17];
    __shared__ float bets[256];
    __shared__ float bkls[256];
    __shared__ float partS1[4][16];
    __shared__ float partS2[4][16];
    __shared__ float partS3[4];
    __shared__ float grot[CK];

    if (t < CK) uish[t] = wsUT[(b*CK + t)*CN + i];
    __syncthreads();

    // ---- Phase A ----
    const float* uTb = wsUT + b*CK*CN;
    float d[CK];
    #pragma unroll
    for (int cc = 0; cc < CK; ++cc) d[cc] = uish[cc] - uTb[cc*CN + t];

    h2_t dh[8];
    #pragma unroll
    for (int q = 0; q < 8; ++q) {
        h2_t v; v.x = (_Float16)d[2*q]; v.y = (_Float16)d[2*q+1];
        dh[q] = v;
    }

    // h[rr] = W row rr . d  — two uint4 loads (8 half2) per row, fdot2 accum
    const uint4* Wb = ((const uint4*)wsW16) + (size_t)b*32*CN + t;
    float h[CK];
    float kl = 0.f;
    #pragma unroll
    for (int rr = 0; rr < CK; ++rr) {
        const uint4 w0 = Wb[(size_t)(rr*2    )*CN];
        const uint4 w1 = Wb[(size_t)(rr*2 + 1)*CN];
        float acc = 0.f;
        acc = FDOT2(as_h2(w0.x), dh[0], acc);
        acc = FDOT2(as_h2(w0.y), dh[1], acc);
        acc = FDOT2(as_h2(w0.z), dh[2], acc);
        acc = FDOT2(as_h2(w0.w), dh[3], acc);
        acc = FDOT2(as_h2(w1.x), dh[4], acc);
        acc = FDOT2(as_h2(w1.y), dh[5], acc);
        acc = FDOT2(as_h2(w1.z), dh[6], acc);
        acc = FDOT2(as_h2(w1.w), dh[7], acc);
        h[rr] = acc;
        Hs[t][rr] = acc;
        kl += acc * d[rr];
    }
    kl *= 0.5f;

    const float bt = beta[(b*CN + i)*CN + t];
    bets[t] = bt;
    bkls[t] = bt * kl;
    __syncthreads();

    // ---- Phase B: thread = (jg = t>>4, k = t&15) ----
    {
        const int k  = t & 15;
        const int jg = t >> 4;
        float s1p = 0.f, s2p = 0.f, s3p = 0.f;
        #pragma unroll
        for (int s = 0; s < 16; ++s) {
            const int jj = jg*16 + s;
            const float hv = Hs[jj][k];
            const float be = bets[jj];
            const float bk = bkls[jj];
            s1p += be * hv;
            s2p += bk * hv;
            s3p += bk;
        }
        s1p += __shfl_down(s1p, 16);  s1p += __shfl_down(s1p, 32);
        s2p += __shfl_down(s2p, 16);  s2p += __shfl_down(s2p, 32);
        s3p += __shfl_down(s3p, 16);  s3p += __shfl_down(s3p, 32);

        const int lane = t & 63;
        const int wv   = t >> 6;
        if (lane < 16) {
            partS1[wv][lane] = s1p;
            partS2[wv][lane] = s2p;
            if (lane == 0) partS3[wv] = s3p;
        }
    }
    __syncthreads();

    // ---- Phase C ----
    if (t < CK) {
        const float s1 = partS1[0][t] + partS1[1][t] + partS1[2][t] + partS1[3][t];
        const float s2 = partS2[0][t] + partS2[1][t] + partS2[2][t] + partS2[3][t];
        const float s3 = partS3[0] + partS3[1] + partS3[2] + partS3[3];
        grot[t] = F_LAM*s1 + (F_LAM/F_KAPPA)*(s2 - s3*s1);
    }
    __syncthreads();

    // ---- Epilogue ----
    if (t < CK) {
        const int rr = t;
        const float* Ri = wsR + bi*256;
        float acc = 0.f;
        #pragma unroll
        for (int cc = 0; cc < CK; ++cc) acc += Ri[rr*CK+cc] * grot[cc];

        const int idx = bi*CK + rr;
        const float mq = mu_q[idx];
        const float sq = sigma_q[idx];
        const float mp = mu_p[idx];
        const float sp = sigma_p[idx];
        const float sps = fmaxf(sp, F_EPS);
        const float sqs = fmaxf(sq, F_EPS);

        const float gmu = F_ALPHA*(mq - mp)/sps + acc;
        const float gsg = F_ALPHA*0.5f*(1.0f/sps - 1.0f/sqs);

        float nmu = sqs * gmu;
        float nsg = 0.5f * sqs * sqs * gsg;
        nmu = fminf(fmaxf(nmu, -F_GCLIP), F_GCLIP);
        nsg = fminf(fmaxf(nsg, -F_GCLIP), F_GCLIP);

        const float step = lr[0];
        out[idx]             = mq - step*nmu;                 // mu_new
        out[CB*CN*CK + idx]  = fmaxf(sq - step*nsg, F_EPS);   // sigma_new
    }
}

extern "C" void kernel_launch(void* const* d_in, const int* in_sizes, int n_in,
                              void* d_out, int out_size, void* d_ws, size_t ws_size,
                              hipStream_t stream) {
    const float* mu_q    = (const float*)d_in[0];
    const float* sigma_q = (const float*)d_in[1];
    const float* mu_p    = (const float*)d_in[2];
    const float* sigma_p = (const float*)d_in[3];
    const float* beta    = (const float*)d_in[4];
    const float* phi     = (const float*)d_in[5];
    const float* gens    = (const float*)d_in[6];
    const float* lr      = (const float*)d_in[7];
    float* out = (float*)d_out;

    float*    wsR   = (float*)d_ws;                    // [b][n][16][16] fp32
    unsigned* wsW16 = (unsigned*)(wsR + CB*CN*CK*CK);  // [b][g<32][n][8 fp16] = 512KB
    float*    wsUT  = (float*)((char*)wsW16 + (size_t)CB*32*CN*16);

    vfe_prep_kernel<<<CB*CN, 256, 0, stream>>>(mu_q, sigma_q, phi, gens,
                                               wsR, wsW16, wsUT);
    vfe_pair_kernel<<<CB*CN, 256, 0, stream>>>(mu_q, sigma_q, mu_p, sigma_p, beta, lr,
                                               wsR, wsW16, wsUT, out);
}